// Round 5
// baseline (193.032 us; speedup 1.0000x reference)
//
#include <hip/hip_runtime.h>
#include <math.h>

// Problem constants: B=1048576, DX=32, DS=16, H=128, K=64, NSN=4
#define DXc 32
#define DSc 16
#define Hc  128
#define Kc  64
#define NSNc 4

// ============================ Kernel A =====================================
// tune[b] = sigmoid(hidden[b,:] . W_tune + b_tune)
// Wave-cooperative GEMV: 32 lanes per row, each lane one float4 of the row.
// Wave reads 1 KB contiguous per pass (2 rows). Pure streaming reduction.
__global__ __launch_bounds__(256, 4) void tune_kernel(
    const float* __restrict__ hidden,
    const float* __restrict__ W_tune,
    const float* __restrict__ b_tune,
    float* __restrict__ tune,
    int n)
{
    const int lane = threadIdx.x & 63;
    const int c = lane & 31;   // float4 column within row
    const int g = lane >> 5;   // row parity within the pass (0 or 1)

    const float4 wt = reinterpret_cast<const float4*>(W_tune)[c];
    const float bt = b_tune[0];

    const int waveGlobal = (int)((blockIdx.x * 256 + threadIdx.x) >> 6);
    const int nWaves = (int)((gridDim.x * 256) >> 6);
    const int nPass = (n + 1) >> 1;   // 2 rows per pass

    const float4* h4 = reinterpret_cast<const float4*>(hidden);

    for (int p = waveGlobal; p < nPass; p += 4 * nWaves) {
        float4 v[4];
        long long rowk[4];
#pragma unroll
        for (int k = 0; k < 4; ++k) {
            const int pk = p + k * nWaves;
            const long long row = (long long)2 * pk + g;
            rowk[k] = row;
            if (pk < nPass && row < n)
                v[k] = h4[row * (Hc / 4) + c];
            else
                v[k] = make_float4(0.f, 0.f, 0.f, 0.f);
        }
#pragma unroll
        for (int k = 0; k < 4; ++k) {
            const int pk = p + k * nWaves;
            if (pk >= nPass) break;
            float acc = v[k].x * wt.x;
            acc = fmaf(v[k].y, wt.y, acc);
            acc = fmaf(v[k].z, wt.z, acc);
            acc = fmaf(v[k].w, wt.w, acc);
            // butterfly over the 32-lane group (masks < 32 stay in-half)
#pragma unroll
            for (int m = 1; m < 32; m <<= 1)
                acc += __shfl_xor(acc, m, 64);
            if (c == 0 && rowk[k] < n) {
                const float xt = 1.0f / (1.0f + __expf(-(acc + bt)));
                tune[rowk[k]] = xt;
            }
        }
    }
}

// ============================ Kernel B =====================================
// Per-thread row: argmin cluster (EXACT round-1 arithmetic) + combined SN dot.
__global__ __launch_bounds__(256, 4) void snb_kernel(
    const float* __restrict__ x,
    const float* __restrict__ s,
    const float* __restrict__ naive_pred,
    const float* __restrict__ tune,
    const float* __restrict__ centers,
    const float* __restrict__ W_sn,
    const float* __restrict__ b_sn,
    const float* __restrict__ rsw,
    float* __restrict__ out,
    int n)
{
    // Combined SN weights: Wc[c][j] = sum_n rsw[c,n] * W_sn[n,c,j]
    //                      bc[c]    = sum_n rsw[c,n] * b_sn[n,c]
    __shared__ float sWc[Kc][DSc + 1];
    __shared__ float sbc[Kc];
    __shared__ float sc2[Kc];

    const int tid = threadIdx.x;

    for (int e = tid; e < Kc * DSc; e += 256) {
        const int c = e >> 4;
        const int j = e & 15;
        float acc = 0.f;
#pragma unroll
        for (int nn = 0; nn < NSNc; ++nn)
            acc = fmaf(rsw[c * NSNc + nn], W_sn[(nn * Kc + c) * DSc + j], acc);
        sWc[c][j] = acc;
    }
    if (tid < Kc) {
        const int c = tid;
        float accb = 0.f;
#pragma unroll
        for (int nn = 0; nn < NSNc; ++nn)
            accb = fmaf(rsw[c * NSNc + nn], b_sn[nn * Kc + c], accb);
        sbc[c] = accb;
        float c2 = 0.f;
#pragma unroll
        for (int d = 0; d < DXc; ++d) {
            const float cv = centers[c * DXc + d];
            c2 = fmaf(cv, cv, c2);
        }
        sc2[c] = c2;
    }
    __syncthreads();

    const size_t b = (size_t)blockIdx.x * 256 + tid;
    if (b >= (size_t)n) return;

    // ---- x row into registers (8x float4; row = 128 B = one L1 line) ----
    float xr[DXc];
    {
        const float4* x4 = reinterpret_cast<const float4*>(x + b * DXc);
#pragma unroll
        for (int i = 0; i < DXc / 4; ++i) {
            const float4 v = x4[i];
            xr[i * 4 + 0] = v.x; xr[i * 4 + 1] = v.y;
            xr[i * 4 + 2] = v.z; xr[i * 4 + 3] = v.w;
        }
    }

    const float x_tune = tune[b];

    // ---- argmin_k ( c2[k] - 2 * x . centers[k] ) ----
    // EXACT round-1 arithmetic: single sequential accumulator, ascending d,
    // ascending k with strict <. argmin is rounding-sensitive on near-ties.
    int bestk = 0;
    float bestd = INFINITY;
#pragma unroll 2
    for (int k = 0; k < Kc; ++k) {
        float dot = 0.f;
#pragma unroll
        for (int d = 0; d < DXc; ++d)
            dot = fmaf(xr[d], centers[k * DXc + d], dot);
        const float dist = fmaf(-2.0f, dot, sc2[k]);
        if (dist < bestd) { bestd = dist; bestk = k; }
    }

    // ---- combined SN dot (s loaded after dist, as in round 1) ----
    float snacc = sbc[bestk];
    {
        const float4* s4 = reinterpret_cast<const float4*>(s + b * DSc);
#pragma unroll
        for (int i = 0; i < DSc / 4; ++i) {
            const float4 v = s4[i];
            snacc = fmaf(v.x, sWc[bestk][i * 4 + 0], snacc);
            snacc = fmaf(v.y, sWc[bestk][i * 4 + 1], snacc);
            snacc = fmaf(v.z, sWc[bestk][i * 4 + 2], snacc);
            snacc = fmaf(v.w, sWc[bestk][i * 4 + 3], snacc);
        }
    }

    const float np_ = naive_pred[b];
    out[b] = snacc + x_tune * (np_ - snacc);
}

extern "C" void kernel_launch(void* const* d_in, const int* in_sizes, int n_in,
                              void* d_out, int out_size, void* d_ws, size_t ws_size,
                              hipStream_t stream) {
    const float* x          = (const float*)d_in[0];
    const float* s          = (const float*)d_in[1];
    const float* hidden     = (const float*)d_in[2];
    const float* naive_pred = (const float*)d_in[3];
    const float* centers    = (const float*)d_in[4];
    const float* W_tune     = (const float*)d_in[5];
    const float* b_tune     = (const float*)d_in[6];
    const float* W_sn       = (const float*)d_in[7];
    const float* b_sn       = (const float*)d_in[8];
    const float* rsw        = (const float*)d_in[9];
    float* out  = (float*)d_out;
    float* tune = (float*)d_ws;   // n floats of scratch

    const int n = in_sizes[3];  // B

    // Kernel A: 2048 blocks = 8192 waves; 64 passes (2 rows) per wave.
    tune_kernel<<<2048, 256, 0, stream>>>(hidden, W_tune, b_tune, tune, n);

    // Kernel B: one thread per row.
    const int blocks = (n + 255) / 256;
    snb_kernel<<<blocks, 256, 0, stream>>>(x, s, naive_pred, tune, centers,
                                           W_sn, b_sn, rsw, out, n);
}